// Round 2
// baseline (144.652 us; speedup 1.0000x reference)
//
#include <hip/hip_runtime.h>
#include <hip/hip_bf16.h>

// Attention: B=512, T=128, C=512, H=64.  out[b,t,h] f32.
// R2: one 8-wave block per batch element (16 rows/wave). No X LDS staging —
// QKV-projection A-fragments load straight from global (per-wave rows, no
// cross-wave X reuse). LDS 48KB = Q|K|V^T (bf16, XOR-swizzled); P overlays
// Q|K in phase 3. Prep kernel converts W (f32) -> bf16 into d_ws (192 KB).

#define TT 128
#define CC 512
#define HH 64

typedef __attribute__((ext_vector_type(8))) short bf16x8;
typedef __attribute__((ext_vector_type(4))) float f32x4;

__device__ __forceinline__ ushort f2bf(float f) {
    union { float f; unsigned u; } v; v.f = f;
    unsigned r = v.u + 0x7fffu + ((v.u >> 16) & 1u);  // RNE
    return (ushort)(r >> 16);
}

// ---- prep: Wq,Wk,Wv [64][512] f32 -> ws as bf16 [3][64][512] ----
__global__ void wconv_kernel(const float* __restrict__ wq,
                             const float* __restrict__ wk,
                             const float* __restrict__ wv,
                             ushort* __restrict__ wbf) {
    int idx = blockIdx.x * 256 + threadIdx.x;      // 0..98303
    int w = idx >> 15;
    int rem = idx & 32767;
    const float* src = (w == 0) ? wq : ((w == 1) ? wk : wv);
    wbf[idx] = f2bf(src[rem]);
}

__launch_bounds__(512, 6)
__global__ void attn_kernel(const float* __restrict__ x,
                            const ushort* __restrict__ wbf,
                            float* __restrict__ out) {
    // 48 KB LDS -> 3 blocks/CU (with VGPR<=85): qs|ks|vst; ps overlays qs+ks.
    __shared__ __align__(16) ushort sm[3 * 128 * 64];
    ushort* qs  = sm;                // [128][64]  swizzled: col ^ ((row&7)<<3)
    ushort* ks  = sm + 8192;         // [128][64]  swizzled
    ushort* vst = sm + 16384;        // [64][128]  V transposed [h][t], swizzled
    ushort* ps  = sm;                // [128][128] P overlay (phase 3), swizzled

    const int tid  = threadIdx.x;
    const int wave = tid >> 6;
    const int lane = tid & 63;
    const int lq   = lane >> 4;     // 0..3
    const int lr   = lane & 15;
    const int b    = blockIdx.x;
    const int row0 = wave * 16;     // this wave owns output rows row0..row0+15

    const float* xb   = x + (size_t)b * (TT * CC);
    const float* xrow = xb + (row0 + lr) * CC + lq * 8;

    const f32x4 fzero = {0.f, 0.f, 0.f, 0.f};

    // ---------------- Phase 1: Q,K,V = X @ W^T (12 n-tiles of 16) --------
    f32x4 acc[12];
    #pragma unroll
    for (int j = 0; j < 12; ++j) acc[j] = fzero;

    #pragma unroll 2
    for (int kt = 0; kt < 16; ++kt) {           // K sub-steps of 32
        float4 v0 = *(const float4*)(xrow + kt * 32);
        float4 v1 = *(const float4*)(xrow + kt * 32 + 4);
        bf16x8 a;
        a[0] = (short)f2bf(v0.x); a[1] = (short)f2bf(v0.y);
        a[2] = (short)f2bf(v0.z); a[3] = (short)f2bf(v0.w);
        a[4] = (short)f2bf(v1.x); a[5] = (short)f2bf(v1.y);
        a[6] = (short)f2bf(v1.z); a[7] = (short)f2bf(v1.w);
        int cg = kt * 32 + lq * 8;
        #pragma unroll
        for (int nt = 0; nt < 12; ++nt) {
            int w = nt >> 2;
            int h = ((nt & 3) << 4) + lr;
            bf16x8 bb = *(const bf16x8*)&wbf[(w << 15) + h * 512 + cg];
            acc[nt] = __builtin_amdgcn_mfma_f32_16x16x32_bf16(a, bb, acc[nt], 0, 0, 0);
        }
    }

    // write Q,K (swizzled [t][h]) and V transposed (swizzled [h][t]) to LDS
    #pragma unroll
    for (int nt = 0; nt < 12; ++nt) {
        #pragma unroll
        for (int j = 0; j < 4; ++j) {
            int t = row0 + lq * 4 + j;
            int h = ((nt & 3) << 4) + lr;
            ushort v = f2bf(acc[nt][j]);
            if (nt < 4)      qs[t * 64 + (h ^ ((t & 7) << 3))] = v;
            else if (nt < 8) ks[t * 64 + (h ^ ((t & 7) << 3))] = v;
            else             vst[h * 128 + (t ^ ((h & 7) << 3))] = v;
        }
    }
    __syncthreads();

    // ---------------- Phase 2: S = Q K^T, scale, causal softmax ----------
    f32x4 s[8];
    #pragma unroll
    for (int j = 0; j < 8; ++j) s[j] = fzero;

    #pragma unroll
    for (int kt = 0; kt < 2; ++kt) {
        int h0 = kt * 32 + lq * 8;
        int t  = row0 + lr;
        bf16x8 a = *(const bf16x8*)&qs[t * 64 + (h0 ^ ((t & 7) << 3))];
        #pragma unroll
        for (int nt = 0; nt < 8; ++nt) {
            int sc = nt * 16 + lr;
            bf16x8 bb = *(const bf16x8*)&ks[sc * 64 + (h0 ^ ((sc & 7) << 3))];
            s[nt] = __builtin_amdgcn_mfma_f32_16x16x32_bf16(a, bb, s[nt], 0, 0, 0);
        }
    }

    float rinv[4];
    #pragma unroll
    for (int j = 0; j < 4; ++j) {
        int t = row0 + lq * 4 + j;             // block-local row (0..127)
        float m = -1e30f;
        #pragma unroll
        for (int nt = 0; nt < 8; ++nt) {
            int sc = nt * 16 + lr;
            float v = s[nt][j] * 0.125f;
            v = (sc <= t) ? v : -1e30f;        // causal mask
            s[nt][j] = v;
            m = fmaxf(m, v);
        }
        m = fmaxf(m, __shfl_xor(m, 1));
        m = fmaxf(m, __shfl_xor(m, 2));
        m = fmaxf(m, __shfl_xor(m, 4));
        m = fmaxf(m, __shfl_xor(m, 8));
        float sum = 0.f;
        #pragma unroll
        for (int nt = 0; nt < 8; ++nt) {
            float p = __expf(s[nt][j] - m);
            s[nt][j] = p;
            sum += p;
        }
        sum += __shfl_xor(sum, 1);
        sum += __shfl_xor(sum, 2);
        sum += __shfl_xor(sum, 4);
        sum += __shfl_xor(sum, 8);
        rinv[j] = 1.0f / sum;                  // deferred normalization
    }

    __syncthreads();   // all QK reads of qs/ks done before P overlay writes

    #pragma unroll
    for (int j = 0; j < 4; ++j) {
        int t = row0 + lq * 4 + j;
        #pragma unroll
        for (int nt = 0; nt < 8; ++nt) {
            int sc = nt * 16 + lr;
            ps[t * 128 + (sc ^ ((t & 7) << 3))] = f2bf(s[nt][j]);
        }
    }
    __syncthreads();

    // ---------------- Phase 3: O = P V ------------------------------------
    f32x4 o[4];
    #pragma unroll
    for (int j = 0; j < 4; ++j) o[j] = fzero;

    #pragma unroll
    for (int ksv = 0; ksv < 4; ++ksv) {
        int s0 = ksv * 32 + lq * 8;
        int t  = row0 + lr;
        bf16x8 a = *(const bf16x8*)&ps[t * 128 + (s0 ^ ((t & 7) << 3))];
        #pragma unroll
        for (int nt = 0; nt < 4; ++nt) {
            int h = nt * 16 + lr;
            bf16x8 bb = *(const bf16x8*)&vst[h * 128 + (s0 ^ ((h & 7) << 3))];
            o[nt] = __builtin_amdgcn_mfma_f32_16x16x32_bf16(a, bb, o[nt], 0, 0, 0);
        }
    }

    float* ob = out + (size_t)b * (TT * HH);
    #pragma unroll
    for (int nt = 0; nt < 4; ++nt)
        #pragma unroll
        for (int j = 0; j < 4; ++j) {
            int t = row0 + lq * 4 + j;
            int h = nt * 16 + lr;
            ob[t * HH + h] = o[nt][j] * rinv[j];
        }
}

extern "C" void kernel_launch(void* const* d_in, const int* in_sizes, int n_in,
                              void* d_out, int out_size, void* d_ws, size_t ws_size,
                              hipStream_t stream) {
    const float* x  = (const float*)d_in[0];
    const float* wq = (const float*)d_in[1];
    const float* wk = (const float*)d_in[2];
    const float* wv = (const float*)d_in[3];
    float* o = (float*)d_out;
    ushort* wbf = (ushort*)d_ws;    // needs 3*64*512*2 = 196608 bytes

    (void)in_sizes; (void)n_in; (void)out_size; (void)ws_size;

    wconv_kernel<<<384, 256, 0, stream>>>(wq, wk, wv, wbf);
    attn_kernel<<<512, 512, 0, stream>>>(x, wbf, o);
}

// Round 3
// 110.425 us; speedup vs baseline: 1.3100x; 1.3100x over previous
//
#include <hip/hip_runtime.h>
#include <hip/hip_bf16.h>

// Attention: B=512, T=128, C=512, H=64. out[b,t,h] f32.
// R3: three-kernel split.
//  1) wpack:  W (3x[64][512] f32) -> bf16 MFMA-fragment-packed into ws.
//  2) qkv:    QKV = X @ W^T, bf16 planes [3][65536][64] in ws. No LDS/barriers;
//             32 rows/wave, B-frags are contiguous coalesced 16B/lane loads.
//  3) attn:   per batch element: stage Q/K/V^T into swizzled LDS, QK^T,
//             in-register causal softmax (deferred normalization), PV, f32 out.

#define TT 128
#define CC 512
#define HH 64

typedef __attribute__((ext_vector_type(8))) short bf16x8;
typedef __attribute__((ext_vector_type(8))) ushort u16x8;
typedef __attribute__((ext_vector_type(4))) float f32x4;

#define QKV_PLANE 4194304           // 65536*64 elems per plane
#define WPK_ELEMS 98304             // 3*64*512

__device__ __forceinline__ ushort f2bf(float f) {
    union { float f; unsigned u; } v; v.f = f;
    unsigned r = v.u + 0x7fffu + ((v.u >> 16) & 1u);  // RNE
    return (ushort)(r >> 16);
}

// ---- wpack: packed fragment p = ((nt*16+kt)*64 + lane)*8 + j, nt=w*4+nt4 ----
// value = W_w[h][c], h = nt4*16 + (lane&15), c = kt*32 + (lane>>4)*8 + j
__global__ void wpack_kernel(const float* __restrict__ wq,
                             const float* __restrict__ wk,
                             const float* __restrict__ wv,
                             ushort* __restrict__ wpk) {
    int p = blockIdx.x * 256 + threadIdx.x;   // 0..98303
    int j  = p & 7;
    int l  = (p >> 3) & 63;
    int kt = (p >> 9) & 15;
    int nt4 = (p >> 13) & 3;
    int w  = p >> 15;
    const float* src = (w == 0) ? wq : ((w == 1) ? wk : wv);
    int h = nt4 * 16 + (l & 15);
    int c = kt * 32 + ((l >> 4) << 3) + j;
    wpk[p] = f2bf(src[h * 512 + c]);
}

// ---- qkv: each wave computes 32 rows x 192 cols; 2048 waves ----
__global__ void qkv_kernel(const float* __restrict__ x,
                           const ushort* __restrict__ wpk,
                           ushort* __restrict__ qkv) {
    const int tid  = threadIdx.x;
    const int wave = tid >> 6;
    const int lane = tid & 63;
    const int lq   = lane >> 4;
    const int lr   = lane & 15;
    const long row0 = ((long)blockIdx.x * 4 + wave) * 32;

    const float* xr0 = x + (row0 + lr) * CC + lq * 8;
    const float* xr1 = x + (row0 + 16 + lr) * CC + lq * 8;

    const f32x4 fzero = {0.f, 0.f, 0.f, 0.f};
    f32x4 acc[2][12];
    #pragma unroll
    for (int i = 0; i < 2; ++i)
        #pragma unroll
        for (int j = 0; j < 12; ++j) acc[i][j] = fzero;

    #pragma unroll 2
    for (int kt = 0; kt < 16; ++kt) {
        float4 v0 = *(const float4*)(xr0 + kt * 32);
        float4 v1 = *(const float4*)(xr0 + kt * 32 + 4);
        float4 v2 = *(const float4*)(xr1 + kt * 32);
        float4 v3 = *(const float4*)(xr1 + kt * 32 + 4);
        bf16x8 a0, a1;
        a0[0] = (short)f2bf(v0.x); a0[1] = (short)f2bf(v0.y);
        a0[2] = (short)f2bf(v0.z); a0[3] = (short)f2bf(v0.w);
        a0[4] = (short)f2bf(v1.x); a0[5] = (short)f2bf(v1.y);
        a0[6] = (short)f2bf(v1.z); a0[7] = (short)f2bf(v1.w);
        a1[0] = (short)f2bf(v2.x); a1[1] = (short)f2bf(v2.y);
        a1[2] = (short)f2bf(v2.z); a1[3] = (short)f2bf(v2.w);
        a1[4] = (short)f2bf(v3.x); a1[5] = (short)f2bf(v3.y);
        a1[6] = (short)f2bf(v3.z); a1[7] = (short)f2bf(v3.w);
        const ushort* wb = wpk + kt * 512 + lane * 8;
        #pragma unroll
        for (int nt = 0; nt < 12; ++nt) {
            bf16x8 bb = *(const bf16x8*)(wb + nt * 8192);   // (nt*16)*512
            acc[0][nt] = __builtin_amdgcn_mfma_f32_16x16x32_bf16(a0, bb, acc[0][nt], 0, 0, 0);
            acc[1][nt] = __builtin_amdgcn_mfma_f32_16x16x32_bf16(a1, bb, acc[1][nt], 0, 0, 0);
        }
    }

    #pragma unroll
    for (int mt = 0; mt < 2; ++mt)
        #pragma unroll
        for (int nt = 0; nt < 12; ++nt)
            #pragma unroll
            for (int j = 0; j < 4; ++j) {
                long R = row0 + mt * 16 + lq * 4 + j;
                int h = (nt & 3) * 16 + lr;
                qkv[(size_t)(nt >> 2) * QKV_PLANE + R * 64 + h] = f2bf(acc[mt][nt][j]);
            }
}

// ---- attn: one block (4 waves) per batch element ----
__launch_bounds__(256)
__global__ void attn_kernel(const ushort* __restrict__ qkv,
                            float* __restrict__ out) {
    // 48 KB LDS -> 3 blocks/CU. ps overlays qs+ks in phase 3.
    __shared__ __align__(16) ushort sm[3 * 128 * 64];
    ushort* qs  = sm;                // [128][64]  swizzled: col ^ ((row&7)<<3)
    ushort* ks  = sm + 8192;         // [128][64]  swizzled
    ushort* vst = sm + 16384;        // [64][128]  V^T [h][t], swizzled on t
    ushort* ps  = sm;                // [128][128] P overlay, swizzled

    const int tid  = threadIdx.x;
    const int wave = tid >> 6;
    const int lane = tid & 63;
    const int lq   = lane >> 4;
    const int lr   = lane & 15;
    const int b    = blockIdx.x;
    const int row0 = wave * 32;

    const ushort* qp = qkv + (size_t)b * 8192;
    const ushort* kp = qkv + QKV_PLANE + (size_t)b * 8192;
    const ushort* vp = qkv + 2 * (size_t)QKV_PLANE + (size_t)b * 8192;

    // stage Q,K (row-major swizzled) and V transposed
    #pragma unroll
    for (int it = 0; it < 4; ++it) {
        int v = it * 256 + tid;          // ushort8 index 0..1023
        int r = v >> 3;
        int c = (v & 7) * 8;
        int sw = r * 64 + (c ^ ((r & 7) << 3));
        *(u16x8*)&qs[sw] = *(const u16x8*)(qp + v * 8);
        *(u16x8*)&ks[sw] = *(const u16x8*)(kp + v * 8);
        u16x8 v8 = *(const u16x8*)(vp + v * 8);
        #pragma unroll
        for (int k = 0; k < 8; ++k) {
            int h = c + k;
            vst[h * 128 + (r ^ ((h & 7) << 3))] = v8[k];
        }
    }
    __syncthreads();

    // ---------------- S = Q K^T, scale, causal softmax --------------------
    const f32x4 fzero = {0.f, 0.f, 0.f, 0.f};
    f32x4 s[2][8];
    #pragma unroll
    for (int i = 0; i < 2; ++i)
        #pragma unroll
        for (int j = 0; j < 8; ++j) s[i][j] = fzero;

    #pragma unroll
    for (int kt = 0; kt < 2; ++kt) {
        int h0 = kt * 32 + lq * 8;
        bf16x8 a[2];
        #pragma unroll
        for (int mt = 0; mt < 2; ++mt) {
            int t = row0 + mt * 16 + lr;
            a[mt] = *(const bf16x8*)&qs[t * 64 + (h0 ^ ((t & 7) << 3))];
        }
        #pragma unroll
        for (int nt = 0; nt < 8; ++nt) {
            int sc = nt * 16 + lr;
            bf16x8 bb = *(const bf16x8*)&ks[sc * 64 + (h0 ^ ((sc & 7) << 3))];
            s[0][nt] = __builtin_amdgcn_mfma_f32_16x16x32_bf16(a[0], bb, s[0][nt], 0, 0, 0);
            s[1][nt] = __builtin_amdgcn_mfma_f32_16x16x32_bf16(a[1], bb, s[1][nt], 0, 0, 0);
        }
    }

    float rinv[2][4];
    #pragma unroll
    for (int mt = 0; mt < 2; ++mt) {
        #pragma unroll
        for (int j = 0; j < 4; ++j) {
            int t = row0 + mt * 16 + lq * 4 + j;
            float m = -1e30f;
            #pragma unroll
            for (int nt = 0; nt < 8; ++nt) {
                int sc = nt * 16 + lr;
                float v = s[mt][nt][j] * 0.125f;
                v = (sc <= t) ? v : -1e30f;
                s[mt][nt][j] = v;
                m = fmaxf(m, v);
            }
            m = fmaxf(m, __shfl_xor(m, 1));
            m = fmaxf(m, __shfl_xor(m, 2));
            m = fmaxf(m, __shfl_xor(m, 4));
            m = fmaxf(m, __shfl_xor(m, 8));
            float sum = 0.f;
            #pragma unroll
            for (int nt = 0; nt < 8; ++nt) {
                float p = __expf(s[mt][nt][j] - m);
                s[mt][nt][j] = p;
                sum += p;
            }
            sum += __shfl_xor(sum, 1);
            sum += __shfl_xor(sum, 2);
            sum += __shfl_xor(sum, 4);
            sum += __shfl_xor(sum, 8);
            rinv[mt][j] = 1.0f / sum;              // deferred normalization
        }
    }

    __syncthreads();   // qs/ks reads done before P overlay writes

    #pragma unroll
    for (int mt = 0; mt < 2; ++mt)
        #pragma unroll
        for (int j = 0; j < 4; ++j) {
            int t = row0 + mt * 16 + lq * 4 + j;
            #pragma unroll
            for (int nt = 0; nt < 8; ++nt) {
                int sc = nt * 16 + lr;
                ps[t * 128 + (sc ^ ((t & 7) << 3))] = f2bf(s[mt][nt][j]);
            }
        }
    __syncthreads();

    // ---------------- O = P V --------------------------------------------
    f32x4 o[2][4];
    #pragma unroll
    for (int i = 0; i < 2; ++i)
        #pragma unroll
        for (int j = 0; j < 4; ++j) o[i][j] = fzero;

    #pragma unroll
    for (int ksv = 0; ksv < 4; ++ksv) {
        int s0 = ksv * 32 + lq * 8;
        bf16x8 a[2];
        #pragma unroll
        for (int mt = 0; mt < 2; ++mt) {
            int t = row0 + mt * 16 + lr;
            a[mt] = *(const bf16x8*)&ps[t * 128 + (s0 ^ ((t & 7) << 3))];
        }
        #pragma unroll
        for (int nt = 0; nt < 4; ++nt) {
            int h = nt * 16 + lr;
            bf16x8 bb = *(const bf16x8*)&vst[h * 128 + (s0 ^ ((h & 7) << 3))];
            o[0][nt] = __builtin_amdgcn_mfma_f32_16x16x32_bf16(a[0], bb, o[0][nt], 0, 0, 0);
            o[1][nt] = __builtin_amdgcn_mfma_f32_16x16x32_bf16(a[1], bb, o[1][nt], 0, 0, 0);
        }
    }

    float* ob = out + (size_t)b * (TT * HH);
    #pragma unroll
    for (int mt = 0; mt < 2; ++mt)
        #pragma unroll
        for (int nt = 0; nt < 4; ++nt)
            #pragma unroll
            for (int j = 0; j < 4; ++j) {
                int t = row0 + mt * 16 + lq * 4 + j;
                int h = nt * 16 + lr;
                ob[t * HH + h] = o[mt][nt][j] * rinv[mt][j];
            }
}

extern "C" void kernel_launch(void* const* d_in, const int* in_sizes, int n_in,
                              void* d_out, int out_size, void* d_ws, size_t ws_size,
                              hipStream_t stream) {
    const float* x  = (const float*)d_in[0];
    const float* wq = (const float*)d_in[1];
    const float* wk = (const float*)d_in[2];
    const float* wv = (const float*)d_in[3];
    float* o = (float*)d_out;

    // ws layout: [0, 192K)   packed W fragments (bf16)
    //            [192K, +24M) QKV planes bf16 [3][65536][64]
    ushort* wpk = (ushort*)d_ws;
    ushort* qkv = (ushort*)((char*)d_ws + WPK_ELEMS * 2);

    (void)in_sizes; (void)n_in; (void)out_size; (void)ws_size;

    wpack_kernel<<<384, 256, 0, stream>>>(wq, wk, wv, wpk);
    qkv_kernel<<<512, 256, 0, stream>>>(x, wpk, qkv);
    attn_kernel<<<512, 256, 0, stream>>>(qkv, o);
}

// Round 4
// 69.167 us; speedup vs baseline: 2.0914x; 1.5965x over previous
//
#include <hip/hip_runtime.h>
#include <hip/hip_bf16.h>

// Attention: B=512, T=128, C=512, H=64. out[b,t,h] f32.
// R4: three-kernel split, qkv register-geometry fixed.
//  1) wpack:  W (3x[64][512] f32) -> bf16 MFMA-fragment-packed into ws.
//  2) qkv:    QKV = X @ W^T, bf16 planes [3][65536][64] in ws.
//             16 rows/wave, acc[12] (48 VGPR), __launch_bounds__(256,3)
//             => no spills; 1024 blocks => 4 blocks/CU occupancy ceiling.
//  3) attn:   per batch element: stage Q/K/V^T into swizzled LDS, QK^T,
//             in-register causal softmax (deferred norm), PV, f32 out.

#define TT 128
#define CC 512
#define HH 64

typedef __attribute__((ext_vector_type(8))) short bf16x8;
typedef __attribute__((ext_vector_type(8))) ushort u16x8;
typedef __attribute__((ext_vector_type(4))) float f32x4;

#define QKV_PLANE 4194304           // 65536*64 elems per plane
#define WPK_ELEMS 98304             // 3*64*512

__device__ __forceinline__ ushort f2bf(float f) {
    union { float f; unsigned u; } v; v.f = f;
    unsigned r = v.u + 0x7fffu + ((v.u >> 16) & 1u);  // RNE
    return (ushort)(r >> 16);
}

// ---- wpack: packed fragment p = ((nt*16+kt)*64 + lane)*8 + j, nt=w*4+nt4 ----
// value = W_w[h][c], h = nt4*16 + (lane&15), c = kt*32 + (lane>>4)*8 + j
__global__ void wpack_kernel(const float* __restrict__ wq,
                             const float* __restrict__ wk,
                             const float* __restrict__ wv,
                             ushort* __restrict__ wpk) {
    int p = blockIdx.x * 256 + threadIdx.x;   // 0..98303
    int j  = p & 7;
    int l  = (p >> 3) & 63;
    int kt = (p >> 9) & 15;
    int nt4 = (p >> 13) & 3;
    int w  = p >> 15;
    const float* src = (w == 0) ? wq : ((w == 1) ? wk : wv);
    int h = nt4 * 16 + (l & 15);
    int c = kt * 32 + ((l >> 4) << 3) + j;
    wpk[p] = f2bf(src[h * 512 + c]);
}

// ---- qkv: each wave computes 16 rows x 192 cols; 4096 waves ----
__launch_bounds__(256, 3)
__global__ void qkv_kernel(const float* __restrict__ x,
                           const ushort* __restrict__ wpk,
                           ushort* __restrict__ qkv) {
    const int tid  = threadIdx.x;
    const int wave = tid >> 6;
    const int lane = tid & 63;
    const int lq   = lane >> 4;
    const int lr   = lane & 15;
    const long row0 = ((long)blockIdx.x * 4 + wave) * 16;

    const float* xr = x + (row0 + lr) * CC + lq * 8;

    const f32x4 fzero = {0.f, 0.f, 0.f, 0.f};
    f32x4 acc[12];
    #pragma unroll
    for (int j = 0; j < 12; ++j) acc[j] = fzero;

    #pragma unroll 2
    for (int kt = 0; kt < 16; ++kt) {
        float4 v0 = *(const float4*)(xr + kt * 32);
        float4 v1 = *(const float4*)(xr + kt * 32 + 4);
        bf16x8 a;
        a[0] = (short)f2bf(v0.x); a[1] = (short)f2bf(v0.y);
        a[2] = (short)f2bf(v0.z); a[3] = (short)f2bf(v0.w);
        a[4] = (short)f2bf(v1.x); a[5] = (short)f2bf(v1.y);
        a[6] = (short)f2bf(v1.z); a[7] = (short)f2bf(v1.w);
        const ushort* wb = wpk + kt * 512 + lane * 8;
        #pragma unroll
        for (int nt = 0; nt < 12; ++nt) {
            bf16x8 bb = *(const bf16x8*)(wb + nt * 8192);   // (nt*16)*512
            acc[nt] = __builtin_amdgcn_mfma_f32_16x16x32_bf16(a, bb, acc[nt], 0, 0, 0);
        }
    }

    #pragma unroll
    for (int nt = 0; nt < 12; ++nt)
        #pragma unroll
        for (int j = 0; j < 4; ++j) {
            long R = row0 + lq * 4 + j;
            int h = (nt & 3) * 16 + lr;
            qkv[(size_t)(nt >> 2) * QKV_PLANE + R * 64 + h] = f2bf(acc[nt][j]);
        }
}

// ---- attn: one block (4 waves) per batch element ----
__launch_bounds__(256)
__global__ void attn_kernel(const ushort* __restrict__ qkv,
                            float* __restrict__ out) {
    // 48 KB LDS -> 3 blocks/CU. ps overlays qs+ks in phase 3.
    __shared__ __align__(16) ushort sm[3 * 128 * 64];
    ushort* qs  = sm;                // [128][64]  swizzled: col ^ ((row&7)<<3)
    ushort* ks  = sm + 8192;         // [128][64]  swizzled
    ushort* vst = sm + 16384;        // [64][128]  V^T [h][t], swizzled on t
    ushort* ps  = sm;                // [128][128] P overlay, swizzled

    const int tid  = threadIdx.x;
    const int wave = tid >> 6;
    const int lane = tid & 63;
    const int lq   = lane >> 4;
    const int lr   = lane & 15;
    const int b    = blockIdx.x;
    const int row0 = wave * 32;

    const ushort* qp = qkv + (size_t)b * 8192;
    const ushort* kp = qkv + QKV_PLANE + (size_t)b * 8192;
    const ushort* vp = qkv + 2 * (size_t)QKV_PLANE + (size_t)b * 8192;

    // stage Q,K (row-major swizzled) and V transposed
    #pragma unroll
    for (int it = 0; it < 4; ++it) {
        int v = it * 256 + tid;          // ushort8 index 0..1023
        int r = v >> 3;
        int c = (v & 7) * 8;
        int sw = r * 64 + (c ^ ((r & 7) << 3));
        *(u16x8*)&qs[sw] = *(const u16x8*)(qp + v * 8);
        *(u16x8*)&ks[sw] = *(const u16x8*)(kp + v * 8);
        u16x8 v8 = *(const u16x8*)(vp + v * 8);
        #pragma unroll
        for (int k = 0; k < 8; ++k) {
            int h = c + k;
            vst[h * 128 + (r ^ ((h & 7) << 3))] = v8[k];
        }
    }
    __syncthreads();

    // ---------------- S = Q K^T, scale, causal softmax --------------------
    const f32x4 fzero = {0.f, 0.f, 0.f, 0.f};
    f32x4 s[2][8];
    #pragma unroll
    for (int i = 0; i < 2; ++i)
        #pragma unroll
        for (int j = 0; j < 8; ++j) s[i][j] = fzero;

    #pragma unroll
    for (int kt = 0; kt < 2; ++kt) {
        int h0 = kt * 32 + lq * 8;
        bf16x8 a[2];
        #pragma unroll
        for (int mt = 0; mt < 2; ++mt) {
            int t = row0 + mt * 16 + lr;
            a[mt] = *(const bf16x8*)&qs[t * 64 + (h0 ^ ((t & 7) << 3))];
        }
        #pragma unroll
        for (int nt = 0; nt < 8; ++nt) {
            int sc = nt * 16 + lr;
            bf16x8 bb = *(const bf16x8*)&ks[sc * 64 + (h0 ^ ((sc & 7) << 3))];
            s[0][nt] = __builtin_amdgcn_mfma_f32_16x16x32_bf16(a[0], bb, s[0][nt], 0, 0, 0);
            s[1][nt] = __builtin_amdgcn_mfma_f32_16x16x32_bf16(a[1], bb, s[1][nt], 0, 0, 0);
        }
    }

    float rinv[2][4];
    #pragma unroll
    for (int mt = 0; mt < 2; ++mt) {
        #pragma unroll
        for (int j = 0; j < 4; ++j) {
            int t = row0 + mt * 16 + lq * 4 + j;
            float m = -1e30f;
            #pragma unroll
            for (int nt = 0; nt < 8; ++nt) {
                int sc = nt * 16 + lr;
                float v = s[mt][nt][j] * 0.125f;
                v = (sc <= t) ? v : -1e30f;
                s[mt][nt][j] = v;
                m = fmaxf(m, v);
            }
            m = fmaxf(m, __shfl_xor(m, 1));
            m = fmaxf(m, __shfl_xor(m, 2));
            m = fmaxf(m, __shfl_xor(m, 4));
            m = fmaxf(m, __shfl_xor(m, 8));
            float sum = 0.f;
            #pragma unroll
            for (int nt = 0; nt < 8; ++nt) {
                float p = __expf(s[mt][nt][j] - m);
                s[mt][nt][j] = p;
                sum += p;
            }
            sum += __shfl_xor(sum, 1);
            sum += __shfl_xor(sum, 2);
            sum += __shfl_xor(sum, 4);
            sum += __shfl_xor(sum, 8);
            rinv[mt][j] = 1.0f / sum;              // deferred normalization
        }
    }

    __syncthreads();   // qs/ks reads done before P overlay writes

    #pragma unroll
    for (int mt = 0; mt < 2; ++mt)
        #pragma unroll
        for (int j = 0; j < 4; ++j) {
            int t = row0 + mt * 16 + lq * 4 + j;
            #pragma unroll
            for (int nt = 0; nt < 8; ++nt) {
                int sc = nt * 16 + lr;
                ps[t * 128 + (sc ^ ((t & 7) << 3))] = f2bf(s[mt][nt][j]);
            }
        }
    __syncthreads();

    // ---------------- O = P V --------------------------------------------
    f32x4 o[2][4];
    #pragma unroll
    for (int i = 0; i < 2; ++i)
        #pragma unroll
        for (int j = 0; j < 4; ++j) o[i][j] = fzero;

    #pragma unroll
    for (int ksv = 0; ksv < 4; ++ksv) {
        int s0 = ksv * 32 + lq * 8;
        bf16x8 a[2];
        #pragma unroll
        for (int mt = 0; mt < 2; ++mt) {
            int t = row0 + mt * 16 + lr;
            a[mt] = *(const bf16x8*)&ps[t * 128 + (s0 ^ ((t & 7) << 3))];
        }
        #pragma unroll
        for (int nt = 0; nt < 4; ++nt) {
            int h = nt * 16 + lr;
            bf16x8 bb = *(const bf16x8*)&vst[h * 128 + (s0 ^ ((h & 7) << 3))];
            o[0][nt] = __builtin_amdgcn_mfma_f32_16x16x32_bf16(a[0], bb, o[0][nt], 0, 0, 0);
            o[1][nt] = __builtin_amdgcn_mfma_f32_16x16x32_bf16(a[1], bb, o[1][nt], 0, 0, 0);
        }
    }

    float* ob = out + (size_t)b * (TT * HH);
    #pragma unroll
    for (int mt = 0; mt < 2; ++mt)
        #pragma unroll
        for (int nt = 0; nt < 4; ++nt)
            #pragma unroll
            for (int j = 0; j < 4; ++j) {
                int t = row0 + mt * 16 + lq * 4 + j;
                int h = nt * 16 + lr;
                ob[t * HH + h] = o[mt][nt][j] * rinv[mt][j];
            }
}

extern "C" void kernel_launch(void* const* d_in, const int* in_sizes, int n_in,
                              void* d_out, int out_size, void* d_ws, size_t ws_size,
                              hipStream_t stream) {
    const float* x  = (const float*)d_in[0];
    const float* wq = (const float*)d_in[1];
    const float* wk = (const float*)d_in[2];
    const float* wv = (const float*)d_in[3];
    float* o = (float*)d_out;

    // ws layout: [0, 192K)   packed W fragments (bf16)
    //            [192K, +24M) QKV planes bf16 [3][65536][64]
    ushort* wpk = (ushort*)d_ws;
    ushort* qkv = (ushort*)((char*)d_ws + WPK_ELEMS * 2);

    (void)in_sizes; (void)n_in; (void)out_size; (void)ws_size;

    wpack_kernel<<<384, 256, 0, stream>>>(wq, wk, wv, wpk);
    qkv_kernel<<<1024, 256, 0, stream>>>(x, wpk, qkv);
    attn_kernel<<<512, 256, 0, stream>>>(qkv, o);
}